// Round 5
// baseline (325.173 us; speedup 1.0000x reference)
//
#include <hip/hip_runtime.h>
#include <cstdint>
#include <cstddef>

typedef __bf16 bf16x8 __attribute__((ext_vector_type(8)));
typedef float f32x4 __attribute__((ext_vector_type(4)));
typedef unsigned short u16;
typedef unsigned short u16x8 __attribute__((ext_vector_type(8)));

#define BATCH 4096
#define NE 8

__device__ __forceinline__ u16 f2bf(float f) {
  union { float f; uint32_t u; } v; v.f = f;
  uint32_t u = v.u;
  u += 0x7fffu + ((u >> 16) & 1u);   // RTNE
  return (u16)(u >> 16);
}

__device__ __forceinline__ float bf2f(u16 u) {
  union { uint32_t u; float f; } v; v.u = ((uint32_t)u) << 16;
  return v.f;
}

__device__ __forceinline__ void cast8(const float* src, u16* dst) {
  const float4* p = (const float4*)src;
  float4 a = p[0], b = p[1];
  u16x8 o;
  o[0] = f2bf(a.x); o[1] = f2bf(a.y); o[2] = f2bf(a.z); o[3] = f2bf(a.w);
  o[4] = f2bf(b.x); o[5] = f2bf(b.y); o[6] = f2bf(b.z); o[7] = f2bf(b.w);
  *(u16x8*)dst = o;
}

// One dispatch: h0 = bf16(x); W0/W1/W2 (E,N,K0) fp32 -> Bt (N, E*K0) bf16.
__device__ __forceinline__ void conv_w_chunk(const float* __restrict__ W,
                                             u16* __restrict__ Bt,
                                             int N, int K0, int chunk) {
  int per_row = K0 >> 3;
  int rid = chunk / per_row;             // rid = e*N + o
  int i0 = (chunk - rid * per_row) << 3;
  int e = rid / N;
  int o = rid - e * N;
  cast8(W + (size_t)rid * K0 + i0,
        Bt + (size_t)o * ((size_t)NE * K0) + (size_t)e * K0 + i0);
}

__global__ void prep_kernel(const float* __restrict__ x,
                            const float* __restrict__ W0,
                            const float* __restrict__ W1,
                            const float* __restrict__ W2,
                            u16* __restrict__ h0, u16* __restrict__ Bt0,
                            u16* __restrict__ Bt1, u16* __restrict__ Bt2) {
  int t = blockIdx.x * blockDim.x + threadIdx.x;
  const int C0 = BATCH * 512 / 8;            // x cast:   262144
  const int C1 = C0 + NE * 1024 * 512 / 8;   // W0:      +524288
  const int C2 = C1 + NE * 1024 * 1024 / 8;  // W1:      +1048576
  if (t < C0) {
    cast8(x + (size_t)t * 8, h0 + (size_t)t * 8);
  } else if (t < C1) {
    conv_w_chunk(W0, Bt0, 1024, 512, t - C0);
  } else if (t < C2) {
    conv_w_chunk(W1, Bt1, 1024, 1024, t - C1);
  } else {
    conv_w_chunk(W2, Bt2, 512, 1024, t - C2);
  }
}

// out = [act](sum_s P_s + blend @ Bias), P_s bf16; bf16 or fp32 out.
template<int SLICES, bool ELU_ACT, bool OUT_BF16>
__global__ void combineS_kernel(const u16* __restrict__ P,
                                const float* __restrict__ blend,
                                const float* __restrict__ Bias,
                                void* __restrict__ outp, int N) {
  int t = blockIdx.x * blockDim.x + threadIdx.x;
  int per_row = N >> 3;
  int b = t / per_row;
  int i0 = (t - b * per_row) << 3;
  const size_t slice = (size_t)BATCH * N;
  float v[8] = {0, 0, 0, 0, 0, 0, 0, 0};
  #pragma unroll
  for (int s = 0; s < SLICES; ++s) {
    u16x8 pv = *(const u16x8*)(P + (size_t)s * slice + (size_t)b * N + i0);
    #pragma unroll
    for (int j = 0; j < 8; ++j) v[j] += bf2f(pv[j]);
  }
  const float4* blp = (const float4*)(blend + b * NE);
  float4 u0 = blp[0], u1 = blp[1];
  float bl[8] = {u0.x, u0.y, u0.z, u0.w, u1.x, u1.y, u1.z, u1.w};
  #pragma unroll
  for (int e = 0; e < NE; ++e) {
    const float4* bp = (const float4*)(Bias + (size_t)e * N + i0);
    float4 ba = bp[0], bb = bp[1];
    float bv[8] = {ba.x, ba.y, ba.z, ba.w, bb.x, bb.y, bb.z, bb.w};
    #pragma unroll
    for (int j = 0; j < 8; ++j) v[j] += bl[e] * bv[j];
  }
  if (ELU_ACT) {
    #pragma unroll
    for (int j = 0; j < 8; ++j) v[j] = v[j] > 0.f ? v[j] : expm1f(v[j]);
  }
  if (OUT_BF16) {
    u16x8 o;
    #pragma unroll
    for (int j = 0; j < 8; ++j) o[j] = f2bf(v[j]);
    *(u16x8*)((u16*)outp + (size_t)b * N + i0) = o;
  } else {
    float4* op = (float4*)((float*)outp + (size_t)b * N + i0);
    op[0] = (float4){v[0], v[1], v[2], v[3]};
    op[1] = (float4){v[4], v[5], v[6], v[7]};
  }
}

#define GL2LDS(g, l) __builtin_amdgcn_global_load_lds( \
    (__attribute__((address_space(1))) void*)(g),      \
    (__attribute__((address_space(3))) void*)(l), 16, 0, 0)

// Raw barrier (does NOT drain counters, unlike __syncthreads) + explicit waits.
#define SBAR  asm volatile("s_barrier" ::: "memory")
#define LGKM0 asm volatile("s_waitcnt lgkmcnt(0)" ::: "memory")
#define VMW6  asm volatile("s_waitcnt vmcnt(6)" ::: "memory")
#define VMW0  asm volatile("s_waitcnt vmcnt(0)" ::: "memory")

// Expert-folding GEMM, single-barrier-per-tile deep pipeline:
//   P_z[b,n] = sum_{e in slice z} blend[b,e] * sum_k h[b,k] W[e,n,k]
// BM=256 BN=128 BK=64, 512 thr / 8 waves (4Mx2N), per-wave 64x64 = acc[4][4],
// per-expert acc2[4][4] folded as acc += blend*acc2 at expert boundaries.
// All staging via global_load_lds (pre-swizzled source, linear LDS dest).
// Triple-buffered LDS (3 x 48 KB) + blend = 153 KB -> 1 block/CU, grid = 256.
// Per 64-K tile: issue 6 GL2LDS(t+2) -> 16 ds_read_b128 + 32 MFMA (compiler
// interleaves; fine-grained lgkmcnt auto-emitted) -> counted vmcnt(6) ->
// ONE s_barrier. 32 MFMA per barrier (AITER-like); loads never drained to 0
// in steady state. With triple-buffer + depth-2 prefetch the only hazard is
// buffer recycle at t+3, which the tile-end vmcnt+barrier covers — intra-tile
// barriers (r3) were pure convoy overhead (r3 post-mortem: ~1200 cy/tile).
template<int K0, int EPB>
__global__ __launch_bounds__(512, 2)
void gemm_fold8_kernel(const u16* __restrict__ h, const u16* __restrict__ Bt,
                       const float* __restrict__ blend,
                       u16* __restrict__ P, int N) {
  constexpr int TPE  = K0 / 64;                 // K-tiles per expert
  constexpr int LTPE = (K0 == 512) ? 3 : 4;     // log2(TPE)
  constexpr int NT   = EPB * TPE;               // total K-tiles (even)
  constexpr int EK   = NE * K0;

  // buffer b at b*49152: A tile 256x64 bf16 (32K) @ +0, B tile 128x64 (16K) @ +32768
  __shared__ __align__(16) char SM[147456];
  __shared__ float bls[256 * 9];                // blend, stride 9 (no conflicts)

  const int tid  = threadIdx.x;
  const int lane = tid & 63, w = tid >> 6;
  const int wm   = w >> 1, wn = w & 1;          // 4 x 2 wave grid
  const int lrow = lane & 15, quad = lane >> 4;

  const int row0 = blockIdx.x * 256;
  const int col0 = blockIdx.y * 128;
  const int e0   = blockIdx.z * EPB;

  // stage blend[row0..row0+255, 0..7] into bls (512 thr x float4 = 256 rows)
  {
    const float4 bv = ((const float4*)(blend + (size_t)row0 * NE))[tid];
    int r = tid >> 1, c = (tid & 1) * 4;
    bls[r * 9 + c + 0] = bv.x;
    bls[r * 9 + c + 1] = bv.y;
    bls[r * 9 + c + 2] = bv.z;
    bls[r * 9 + c + 3] = bv.w;
  }

  // staging geometry: sr = row 0..63 per pass, sc = 16B chunk 0..7
  const int sr  = tid >> 3, sc = tid & 7;
  const int tcol = sc ^ (sr & 7);               // XOR-8 chunk swizzle (source side)
  const u16* gA = h + (size_t)(row0 + sr) * K0 + (tcol << 3);   // rows +0/64/128/192
  const u16* gB = Bt + (size_t)(col0 + sr) * EK + (tcol << 3);  // rows +0/64

#define KCOL(T)  (((T) & (TPE - 1)) << 6)
#define KOFFB(T) ((size_t)(e0 + ((T) >> LTPE)) * K0 + KCOL(T))

  // fragment read byte offsets (XOR-8; frag-row&7 == lrow&7)
  const int xr = lrow & 7;
  uint32_t aoff[2][4], boff[2][4];
  #pragma unroll
  for (int kc = 0; kc < 2; ++kc)
    #pragma unroll
    for (int i = 0; i < 4; ++i) {
      aoff[kc][i] = (uint32_t)((wm * 64 + i * 16 + lrow) * 128 +
                               (((kc * 4 + quad) ^ xr) << 4));
      boff[kc][i] = (uint32_t)((wn * 64 + i * 16 + lrow) * 128 +
                               (((kc * 4 + quad) ^ xr) << 4));
    }

  f32x4 acc[4][4], acc2[4][4];
  #pragma unroll
  for (int i = 0; i < 4; ++i)
    #pragma unroll
    for (int j = 0; j < 4; ++j) {
      acc[i][j]  = (f32x4){0.f, 0.f, 0.f, 0.f};
      acc2[i][j] = (f32x4){0.f, 0.f, 0.f, 0.f};
    }

  // ---- prologue: stage tiles 0 (buf0) and 1 (buf1), wait tile0, barrier ----
  {
    const u16* pa = gA;                       // KCOL(0) = 0
    GL2LDS(pa,            SM + (size_t)tid * 16);
    GL2LDS(pa + 64 * K0,  SM + 8192 + (size_t)tid * 16);
    GL2LDS(pa + 128 * K0, SM + 16384 + (size_t)tid * 16);
    GL2LDS(pa + 192 * K0, SM + 24576 + (size_t)tid * 16);
    const u16* pb = gB + (size_t)e0 * K0;
    GL2LDS(pb,            SM + 32768 + (size_t)tid * 16);
    GL2LDS(pb + 64 * EK,  SM + 40960 + (size_t)tid * 16);
    const u16* pa1 = gA + KCOL(1);
    GL2LDS(pa1,            SM + 49152 + (size_t)tid * 16);
    GL2LDS(pa1 + 64 * K0,  SM + 49152 + 8192 + (size_t)tid * 16);
    GL2LDS(pa1 + 128 * K0, SM + 49152 + 16384 + (size_t)tid * 16);
    GL2LDS(pa1 + 192 * K0, SM + 49152 + 24576 + (size_t)tid * 16);
    const u16* pb1 = gB + KOFFB(1);
    GL2LDS(pb1,            SM + 49152 + 32768 + (size_t)tid * 16);
    GL2LDS(pb1 + 64 * EK,  SM + 49152 + 40960 + (size_t)tid * 16);
  }
  VMW6;    // tile-0's 6 loads landed (6 of tile-1 still in flight)
  LGKM0;   // bls writes visible
  SBAR;

// One 64-K tile: 6 GL2LDS(t+2) -> {16 ds_read_b128 + 2x16 MFMA, compiler-
// scheduled} -> optional expert fold -> counted vmcnt(6) -> ONE s_barrier.
#define TILE(T, CUR, TGT)                                                       \
  {                                                                             \
    const int tn2 = (T) + 2;                                                    \
    if (tn2 < NT) {                                                             \
      const u16* pa = gA + KCOL(tn2);                                           \
      GL2LDS(pa,            SM + (TGT) + (size_t)tid * 16);                     \
      GL2LDS(pa + 64 * K0,  SM + (TGT) + 8192 + (size_t)tid * 16);              \
      GL2LDS(pa + 128 * K0, SM + (TGT) + 16384 + (size_t)tid * 16);             \
      GL2LDS(pa + 192 * K0, SM + (TGT) + 24576 + (size_t)tid * 16);             \
      const u16* pb = gB + KOFFB(tn2);                                          \
      GL2LDS(pb,            SM + (TGT) + 32768 + (size_t)tid * 16);             \
      GL2LDS(pb + 64 * EK,  SM + (TGT) + 40960 + (size_t)tid * 16);             \
    }                                                                           \
    _Pragma("unroll")                                                           \
    for (int kc = 0; kc < 2; ++kc) {                                            \
      bf16x8 af[4], bfv[4];                                                     \
      _Pragma("unroll")                                                         \
      for (int i = 0; i < 4; ++i)                                               \
        af[i] = *(const bf16x8*)(SM + (CUR) + aoff[kc][i]);                     \
      _Pragma("unroll")                                                         \
      for (int j = 0; j < 4; ++j)                                               \
        bfv[j] = *(const bf16x8*)(SM + (CUR) + 32768 + boff[kc][j]);            \
      __builtin_amdgcn_s_setprio(1);                                            \
      _Pragma("unroll")                                                         \
      for (int i = 0; i < 4; ++i)                                               \
        _Pragma("unroll")                                                       \
        for (int j = 0; j < 4; ++j)                                             \
          acc2[i][j] = __builtin_amdgcn_mfma_f32_16x16x32_bf16(af[i], bfv[j],   \
                                                           acc2[i][j], 0, 0, 0);\
      __builtin_amdgcn_s_setprio(0);                                            \
    }                                                                           \
    /* expert-boundary fold (amortized over TPE tiles) */                       \
    if ((((T) + 1) & (TPE - 1)) == 0) {                                         \
      const int e_ = e0 + ((T) >> LTPE);                                        \
      _Pragma("unroll")                                                         \
      for (int mt = 0; mt < 4; ++mt) {                                          \
        float bl[4];                                                            \
        _Pragma("unroll")                                                       \
        for (int r = 0; r < 4; ++r)                                             \
          bl[r] = bls[(wm * 64 + mt * 16 + quad * 4 + r) * 9 + e_];             \
        _Pragma("unroll")                                                       \
        for (int nt = 0; nt < 4; ++nt)                                          \
          _Pragma("unroll")                                                     \
          for (int r = 0; r < 4; ++r) {                                         \
            acc[mt][nt][r] += bl[r] * acc2[mt][nt][r];                          \
            acc2[mt][nt][r] = 0.f;                                              \
          }                                                                     \
      }                                                                         \
    }                                                                           \
    if (tn2 < NT) { VMW6; } else { VMW0; }                                      \
    SBAR;                                                                       \
  }

  uint32_t c0 = 0, c1 = 49152, c2 = 98304;
  #pragma unroll 1
  for (int t = 0; t < NT; t += 2) {
    TILE(t,     c0, c2);
    TILE(t + 1, c1, c0);
    const uint32_t tmp = c2; c2 = c1; c1 = c0; c0 = tmp;
  }
#undef TILE
#undef KOFFB
#undef KCOL

  // Coalesced epilogue via per-wave LDS transpose (SM free after final barrier;
  // each wave uses a private 4 KB segment). C/D: col=lane&15, row=quad*4+reg.
  u16* Ps = P + (size_t)blockIdx.z * ((size_t)BATCH * N);
  u16* ls = (u16*)SM + w * 2048;   // 32 rows x 64 cols u16 per wave
  #pragma unroll
  for (int half = 0; half < 2; ++half) {
    #pragma unroll
    for (int mh = 0; mh < 2; ++mh) {
      int mt = half * 2 + mh;
      #pragma unroll
      for (int r = 0; r < 4; ++r) {
        int rloc = mh * 16 + quad * 4 + r;          // 0..31
        #pragma unroll
        for (int nt = 0; nt < 4; ++nt) {
          int col = nt * 16 + lrow;                 // 0..63
          int c8 = (col >> 3) ^ (rloc & 7);         // XOR-8 chunk swizzle
          ls[rloc * 64 + (c8 << 3) + (col & 7)] = f2bf(acc[mt][nt][r]);
        }
      }
    }
    #pragma unroll
    for (int p = 0; p < 4; ++p) {
      int rloc = p * 8 + (lane >> 3);               // 0..31
      int c8 = (lane & 7) ^ (rloc & 7);
      u16x8 v = *(const u16x8*)&ls[rloc * 64 + (c8 << 3)];
      int row = row0 + wm * 64 + half * 32 + rloc;
      int colg = col0 + wn * 64 + ((lane & 7) << 3);
      *(u16x8*)&Ps[(size_t)row * N + colg] = v;
    }
  }
}

extern "C" void kernel_launch(void* const* d_in, const int* in_sizes, int n_in,
                              void* d_out, int out_size, void* d_ws, size_t ws_size,
                              hipStream_t stream) {
  const float* blend = (const float*)d_in[0];
  const float* x  = (const float*)d_in[1];
  const float* W0 = (const float*)d_in[2];
  const float* B0 = (const float*)d_in[3];
  const float* W1 = (const float*)d_in[4];
  const float* B1 = (const float*)d_in[5];
  const float* W2 = (const float*)d_in[6];
  const float* B2 = (const float*)d_in[7];
  float* out = (float*)d_out;

  char* ws = (char*)d_ws;
  u16* hA  = (u16*)ws;                           // h0 (4096x512) then h2 (4096x1024); 8.4 MB
  u16* h1  = (u16*)(ws + 8388608);               // 4096x1024 bf16, 8.4 MB
  u16* Bt0 = (u16*)(ws + 16777216);              // 1024 x 4096 bf16, 8.4 MB
  u16* Bt1 = (u16*)(ws + 25165824);              // 1024 x 8192 bf16, 16.8 MB
  u16* Bt2 = (u16*)(ws + 41943040);              // 512 x 8192 bf16, 8.4 MB
  u16* P   = (u16*)(ws + 50331648);              // bf16 partials (unchanged)

  // prep: cast x -> h0 and convert all three W to bf16 Bt layout (one dispatch)
  prep_kernel<<<9216, 256, 0, stream>>>(x, W0, W1, W2, hA, Bt0, Bt1, Bt2);

  // Layer 0: K0=512, 2 slices x 4 experts; bias+ELU in combine
  gemm_fold8_kernel<512, 4><<<dim3(16, 8, 2), 512, 0, stream>>>(hA, Bt0, blend, P, 1024);
  combineS_kernel<2, true, true><<<2048, 256, 0, stream>>>(P, blend, B0, h1, 1024);

  // Layer 1: K0=1024, 2 slices x 4 experts
  gemm_fold8_kernel<1024, 4><<<dim3(16, 8, 2), 512, 0, stream>>>(h1, Bt1, blend, P, 1024);
  combineS_kernel<2, true, true><<<2048, 256, 0, stream>>>(P, blend, B1, hA, 1024);

  // Layer 2: K0=1024, N=512, 4 slices x 2 experts; linear, fp32 out
  gemm_fold8_kernel<1024, 2><<<dim3(16, 4, 4), 512, 0, stream>>>(hA, Bt2, blend, P, 512);
  combineS_kernel<4, false, false><<<1024, 256, 0, stream>>>(P, blend, B2, out, 512);
}

// Round 6
// 304.708 us; speedup vs baseline: 1.0672x; 1.0672x over previous
//
#include <hip/hip_runtime.h>
#include <cstdint>
#include <cstddef>

typedef __bf16 bf16x8 __attribute__((ext_vector_type(8)));
typedef float f32x4 __attribute__((ext_vector_type(4)));
typedef unsigned short u16;
typedef unsigned short u16x8 __attribute__((ext_vector_type(8)));

#define BATCH 4096
#define NE 8

__device__ __forceinline__ u16 f2bf(float f) {
  union { float f; uint32_t u; } v; v.f = f;
  uint32_t u = v.u;
  u += 0x7fffu + ((u >> 16) & 1u);   // RTNE
  return (u16)(u >> 16);
}

__device__ __forceinline__ float bf2f(u16 u) {
  union { uint32_t u; float f; } v; v.u = ((uint32_t)u) << 16;
  return v.f;
}

__device__ __forceinline__ void cast8(const float* src, u16* dst) {
  const float4* p = (const float4*)src;
  float4 a = p[0], b = p[1];
  u16x8 o;
  o[0] = f2bf(a.x); o[1] = f2bf(a.y); o[2] = f2bf(a.z); o[3] = f2bf(a.w);
  o[4] = f2bf(b.x); o[5] = f2bf(b.y); o[6] = f2bf(b.z); o[7] = f2bf(b.w);
  *(u16x8*)dst = o;
}

// W0/W1/W2 (E,N,K0) fp32 -> Bt (N, E*K0) bf16.
__device__ __forceinline__ void conv_w_chunk(const float* __restrict__ W,
                                             u16* __restrict__ Bt,
                                             int N, int K0, int chunk) {
  int per_row = K0 >> 3;
  int rid = chunk / per_row;             // rid = e*N + o
  int i0 = (chunk - rid * per_row) << 3;
  int e = rid / N;
  int o = rid - e * N;
  cast8(W + (size_t)rid * K0 + i0,
        Bt + (size_t)o * ((size_t)NE * K0) + (size_t)e * K0 + i0);
}

// One dispatch: hh0[b, e*512+k] = bf16(blend[b,e]*x[b,k]); W* -> Bt* bf16.
__global__ void prep_kernel(const float* __restrict__ blend,
                            const float* __restrict__ x,
                            const float* __restrict__ W0,
                            const float* __restrict__ W1,
                            const float* __restrict__ W2,
                            u16* __restrict__ hh0, u16* __restrict__ Bt0,
                            u16* __restrict__ Bt1, u16* __restrict__ Bt2) {
  int t = blockIdx.x * blockDim.x + threadIdx.x;
  const int C0 = BATCH * 512 / 8;            // x-hat:    262144
  const int C1 = C0 + NE * 1024 * 512 / 8;   // W0:      +524288
  const int C2 = C1 + NE * 1024 * 1024 / 8;  // W1:      +1048576
  if (t < C0) {
    int b = t >> 6, i0 = (t & 63) << 3;
    const float4* xp = (const float4*)(x + (size_t)b * 512 + i0);
    float4 a = xp[0], c = xp[1];
    float xv[8] = {a.x, a.y, a.z, a.w, c.x, c.y, c.z, c.w};
    const float4* blp = (const float4*)(blend + (size_t)b * NE);
    float4 u0 = blp[0], u1 = blp[1];
    float bl[8] = {u0.x, u0.y, u0.z, u0.w, u1.x, u1.y, u1.z, u1.w};
    u16* dst = hh0 + (size_t)b * 4096 + i0;
    #pragma unroll
    for (int e = 0; e < NE; ++e) {
      u16x8 o;
      #pragma unroll
      for (int j = 0; j < 8; ++j) o[j] = f2bf(bl[e] * xv[j]);
      *(u16x8*)(dst + (size_t)e * 512) = o;
    }
  } else if (t < C1) {
    conv_w_chunk(W0, Bt0, 1024, 512, t - C0);
  } else if (t < C2) {
    conv_w_chunk(W1, Bt1, 1024, 1024, t - C1);
  } else {
    conv_w_chunk(W2, Bt2, 512, 1024, t - C2);
  }
}

// out = [act](sum_s P_s + blend @ Bias).
// OM=0: fp32 out (final). OM=1: write hhat_next[b, e*N + n] = bf16(bl[e]*v[n]).
template<int SLICES, bool ELU_ACT, int OM>
__global__ void combineS_kernel(const u16* __restrict__ P,
                                const float* __restrict__ blend,
                                const float* __restrict__ Bias,
                                void* __restrict__ outp, int N) {
  int t = blockIdx.x * blockDim.x + threadIdx.x;
  int per_row = N >> 3;
  int b = t / per_row;
  int i0 = (t - b * per_row) << 3;
  const size_t slice = (size_t)BATCH * N;
  float v[8] = {0, 0, 0, 0, 0, 0, 0, 0};
  #pragma unroll
  for (int s = 0; s < SLICES; ++s) {
    u16x8 pv = *(const u16x8*)(P + (size_t)s * slice + (size_t)b * N + i0);
    #pragma unroll
    for (int j = 0; j < 8; ++j) v[j] += bf2f(pv[j]);
  }
  const float4* blp = (const float4*)(blend + b * NE);
  float4 u0 = blp[0], u1 = blp[1];
  float bl[8] = {u0.x, u0.y, u0.z, u0.w, u1.x, u1.y, u1.z, u1.w};
  #pragma unroll
  for (int e = 0; e < NE; ++e) {
    const float4* bp = (const float4*)(Bias + (size_t)e * N + i0);
    float4 ba = bp[0], bb = bp[1];
    float bv[8] = {ba.x, ba.y, ba.z, ba.w, bb.x, bb.y, bb.z, bb.w};
    #pragma unroll
    for (int j = 0; j < 8; ++j) v[j] += bl[e] * bv[j];
  }
  if (ELU_ACT) {
    #pragma unroll
    for (int j = 0; j < 8; ++j) v[j] = v[j] > 0.f ? v[j] : expm1f(v[j]);
  }
  if (OM == 1) {
    u16* hh = (u16*)outp;
    size_t base = (size_t)b * ((size_t)NE * N) + i0;
    #pragma unroll
    for (int e = 0; e < NE; ++e) {
      u16x8 o;
      #pragma unroll
      for (int j = 0; j < 8; ++j) o[j] = f2bf(bl[e] * v[j]);
      *(u16x8*)(hh + base + (size_t)e * N) = o;
    }
  } else {
    float4* op = (float4*)((float*)outp + (size_t)b * N + i0);
    op[0] = (float4){v[0], v[1], v[2], v[3]};
    op[1] = (float4){v[4], v[5], v[6], v[7]};
  }
}

#define GL2LDS(g, l) __builtin_amdgcn_global_load_lds( \
    (__attribute__((address_space(1))) void*)(g),      \
    (__attribute__((address_space(3))) void*)(l), 16, 0, 0)

#define SBAR  asm volatile("s_barrier" ::: "memory")
#define VMW6  asm volatile("s_waitcnt vmcnt(6)" ::: "memory")

// Pure-GEMM 256x256 8-phase template (m201-style, T2+T3+T4+T5):
//   P_z = hhat[:, z*KSL : (z+1)*KSL] @ Bt[:, same]^T  (bf16, fp32 acc)
// BM=BN=256, BK=64, 512 thr / 8 waves (2M x 4N), per-wave 128x64 = acc[8][4].
// Blend is pre-folded into hhat by the producer kernels -> no fold, no acc2.
// Double-buffered LDS 2 x (A 32K + B 32K) = 128 KB, 1 block/CU, grid = 256.
// 8 phases per 2 K-tiles; per phase: {ds_read frag subtile (+B at p0/p4),
// 2 GL2LDS quadrant stages, SBAR, setprio(1) 16 MFMA setprio(0), SBAR};
// counted vmcnt(6) ONLY at phases 4 and 8. Stage plan is quadrant-hazard
// verified: A-quads {0,2} free after p1, {1,3} after p3 (per buffer);
// B free after its p0/p4 read. XOR-8 chunk swizzle, source-side == read-side.
template<int NT>   // K-tiles per block (even, >= 4): KSL = NT*64
__global__ __launch_bounds__(512, 2)
void gemm8p_kernel(const u16* __restrict__ A, const u16* __restrict__ B,
                   u16* __restrict__ P, int N, int KTOT, int KSL) {
  __shared__ __align__(16) char SM[131072];   // buf k @ k*65536: A @+0, B @+32768

  const int tid  = threadIdx.x;
  const int lane = tid & 63, w = tid >> 6;
  const int wm   = w >> 2, wn = w & 3;        // 2M x 4N wave grid
  const int lrow = lane & 15, quad = lane >> 4;

  const int row0 = blockIdx.x * 256;
  const int col0 = blockIdx.y * 256;
  const size_t kb0 = (size_t)blockIdx.z * KSL;

  // staging geometry: 64 rows x 8 chunks per 8 KB load unit
  const int sr = tid >> 3, sc = tid & 7;
  const int tcol = sc ^ (sr & 7);             // XOR-8 source-side swizzle
  const u16* gA = A + ((size_t)(row0 + sr) * KTOT + kb0 + (tcol << 3));
  const u16* gB = B + ((size_t)(col0 + sr) * KTOT + kb0 + (tcol << 3));

#define STA(T, q, BUF) GL2LDS(gA + (size_t)(64 * (q)) * KTOT + (size_t)(T) * 64, \
                              SM + (BUF) * 65536 + (q) * 8192 + (size_t)tid * 16)
#define STB(T, q, BUF) GL2LDS(gB + (size_t)(64 * (q)) * KTOT + (size_t)(T) * 64, \
                              SM + (BUF) * 65536 + 32768 + (q) * 8192 + (size_t)tid * 16)

  // fragment read offsets (XOR-8; frag-row&7 == lrow&7)
  const int xr = lrow & 7;
  const uint32_t arow = (uint32_t)((wm * 128 + lrow) * 128);
  const uint32_t brow = (uint32_t)((wn * 64 + lrow) * 128);
  uint32_t ch[2];
  ch[0] = (uint32_t)((quad ^ xr) << 4);
  ch[1] = (uint32_t)(((4 + quad) ^ xr) << 4);

  f32x4 acc[8][4];
  #pragma unroll
  for (int i = 0; i < 8; ++i)
    #pragma unroll
    for (int j = 0; j < 4; ++j) acc[i][j] = (f32x4){0.f, 0.f, 0.f, 0.f};

  // ---- prologue: tile0 full (8 loads) + tile1 partial (6: B all, A q0,q2) ----
  STA(0, 0, 0); STA(0, 1, 0); STA(0, 2, 0); STA(0, 3, 0);
  STB(0, 0, 0); STB(0, 1, 0); STB(0, 2, 0); STB(0, 3, 0);
  STB(1, 0, 1); STB(1, 1, 1); STB(1, 2, 1); STB(1, 3, 1);
  STA(1, 0, 1); STA(1, 2, 1);
  VMW6;    // tile-0's 8 landed; tile-1's 6 in flight
  SBAR;

// One phase: quadrant q of buffer CUR; optional B reload; 2 staging loads.
#define PHASE(q, CUR, RDB, STAGES)                                              \
  {                                                                             \
    if (RDB) {                                                                  \
      _Pragma("unroll")                                                         \
      for (int nt = 0; nt < 4; ++nt)                                            \
        _Pragma("unroll")                                                       \
        for (int kc = 0; kc < 2; ++kc)                                          \
          bfr[nt][kc] = *(const bf16x8*)(SM + (CUR) + 32768 + brow +            \
                                         nt * 2048 + ch[kc]);                   \
    }                                                                           \
    bf16x8 af[2][2];                                                            \
    _Pragma("unroll")                                                           \
    for (int m2 = 0; m2 < 2; ++m2)                                              \
      _Pragma("unroll")                                                         \
      for (int kc = 0; kc < 2; ++kc)                                            \
        af[m2][kc] = *(const bf16x8*)(SM + (CUR) + arow +                       \
                                      ((q) * 2 + m2) * 2048 + ch[kc]);          \
    STAGES;                                                                     \
    SBAR;                                                                       \
    __builtin_amdgcn_s_setprio(1);                                              \
    _Pragma("unroll")                                                           \
    for (int kc = 0; kc < 2; ++kc)                                              \
      _Pragma("unroll")                                                         \
      for (int m2 = 0; m2 < 2; ++m2)                                            \
        _Pragma("unroll")                                                       \
        for (int nt = 0; nt < 4; ++nt)                                          \
          acc[(q) * 2 + m2][nt] = __builtin_amdgcn_mfma_f32_16x16x32_bf16(      \
              af[m2][kc], bfr[nt][kc], acc[(q) * 2 + m2][nt], 0, 0, 0);         \
    __builtin_amdgcn_s_setprio(0);                                              \
  }

  constexpr int NIT = NT / 2;
  #pragma unroll 1
  for (int j = 0; j < NIT; ++j) {
    const int u = 2 * j;
    const bool sg = (u + 2 < NT);
    bf16x8 bfr[4][2];
    // ---- tile u (buf0), phases 0-3 ----
    PHASE(0, 0, true,  { STA(u + 1, 1, 1); STA(u + 1, 3, 1); });
    SBAR;
    PHASE(1, 0, false, { if (sg) { STB(u + 2, 0, 0); STB(u + 2, 1, 0); } });
    SBAR;
    PHASE(2, 0, false, { if (sg) { STA(u + 2, 0, 0); STA(u + 2, 2, 0); } });
    SBAR;
    PHASE(3, 0, false, { if (sg) { STB(u + 2, 2, 0); STB(u + 2, 3, 0); } });
    VMW6;   // drains through tile u+1's last loads; <=6 of tile u+2 in flight
    SBAR;
    // ---- tile u+1 (buf1), phases 4-7 ----
    PHASE(0, 65536, true,  { if (sg) { STA(u + 2, 1, 0); STA(u + 2, 3, 0); } });
    SBAR;
    PHASE(1, 65536, false, { if (sg) { STB(u + 3, 0, 1); STB(u + 3, 1, 1); } });
    SBAR;
    PHASE(2, 65536, false, { if (sg) { STA(u + 3, 0, 1); STA(u + 3, 2, 1); } });
    SBAR;
    PHASE(3, 65536, false, { if (sg) { STB(u + 3, 2, 1); STB(u + 3, 3, 1); } });
    VMW6;   // drains tile u+2's 8 loads; <=6 of tile u+3 in flight
    SBAR;
  }
#undef PHASE
#undef STA
#undef STB

  // Coalesced epilogue via per-wave LDS transpose (buf0 free; per-wave 4 KB
  // segment; outstanding prefetches target buf1 only — disjoint).
  // C/D: col=lane&15, row=quad*4+reg.
  u16* Ps = P + (size_t)blockIdx.z * ((size_t)BATCH * N);
  u16* ls = (u16*)SM + w * 2048;   // 32 rows x 64 cols u16 per wave
  #pragma unroll
  for (int pass = 0; pass < 4; ++pass) {
    #pragma unroll
    for (int mh = 0; mh < 2; ++mh) {
      int mt = pass * 2 + mh;
      #pragma unroll
      for (int r = 0; r < 4; ++r) {
        int rloc = mh * 16 + quad * 4 + r;          // 0..31
        #pragma unroll
        for (int nt = 0; nt < 4; ++nt) {
          int col = nt * 16 + lrow;                 // 0..63
          int c8 = (col >> 3) ^ (rloc & 7);         // XOR-8 chunk swizzle
          ls[rloc * 64 + (c8 << 3) + (col & 7)] = f2bf(acc[mt][nt][r]);
        }
      }
    }
    #pragma unroll
    for (int p8 = 0; p8 < 4; ++p8) {
      int rloc = p8 * 8 + (lane >> 3);              // 0..31
      int c8 = (lane & 7) ^ (rloc & 7);
      u16x8 v = *(const u16x8*)&ls[rloc * 64 + (c8 << 3)];
      int row = row0 + wm * 128 + pass * 32 + rloc;
      int colg = col0 + wn * 64 + ((lane & 7) << 3);
      *(u16x8*)&Ps[(size_t)row * N + colg] = v;
    }
  }
}

extern "C" void kernel_launch(void* const* d_in, const int* in_sizes, int n_in,
                              void* d_out, int out_size, void* d_ws, size_t ws_size,
                              hipStream_t stream) {
  const float* blend = (const float*)d_in[0];
  const float* x  = (const float*)d_in[1];
  const float* W0 = (const float*)d_in[2];
  const float* B0 = (const float*)d_in[3];
  const float* W1 = (const float*)d_in[4];
  const float* B1 = (const float*)d_in[5];
  const float* W2 = (const float*)d_in[6];
  const float* B2 = (const float*)d_in[7];
  float* out = (float*)d_out;

  char* ws = (char*)d_ws;
  u16* hh1 = (u16*)ws;                    // 4096 x 8192 bf16, 64 MB  [0,   64M)
  u16* hh0 = (u16*)(ws + 67108864);       // 4096 x 4096 bf16, 32 MB  [64M, 96M)
  u16* hh2 = (u16*)(ws + 67108864);       // 4096 x 8192 bf16, 64 MB  [64M,128M) (hh0 dead)
  u16* Bt0 = (u16*)(ws + 134217728);      // 1024 x 4096 bf16, 8.4 MB
  u16* Bt1 = (u16*)(ws + 142606336);      // 1024 x 8192 bf16, 16.8 MB
  u16* Bt2 = (u16*)(ws + 159383552);      // 512 x 8192 bf16,  8.4 MB
  u16* P   = (u16*)(ws + 167772160);      // bf16 partials, 33.6 MB -> end 192 MB

  // prep: hh0 = blend-scaled bf16 x; W0/1/2 -> bf16 Bt layout
  prep_kernel<<<9216, 256, 0, stream>>>(blend, x, W0, W1, W2, hh0, Bt0, Bt1, Bt2);

  // Layer 0: KTOT=4096, 4 K-slices of 1024; bias+ELU+blend-fold in combine
  gemm8p_kernel<16><<<dim3(16, 4, 4), 512, 0, stream>>>(hh0, Bt0, P, 1024, 4096, 1024);
  combineS_kernel<4, true, 1><<<2048, 256, 0, stream>>>(P, blend, B0, hh1, 1024);

  // Layer 1: KTOT=8192, 4 K-slices of 2048
  gemm8p_kernel<32><<<dim3(16, 4, 4), 512, 0, stream>>>(hh1, Bt1, P, 1024, 8192, 2048);
  combineS_kernel<4, true, 1><<<2048, 256, 0, stream>>>(P, blend, B1, hh2, 1024);

  // Layer 2: N=512, KTOT=8192, 8 K-slices of 1024; linear, fp32 out
  gemm8p_kernel<16><<<dim3(16, 2, 8), 512, 0, stream>>>(hh2, Bt2, P, 512, 8192, 1024);
  combineS_kernel<8, false, 0><<<1024, 256, 0, stream>>>(P, blend, B2, out, 512);
}